// Round 1
// 528.965 us; speedup vs baseline: 1.0046x; 1.0046x over previous
//
#include <hip/hip_runtime.h>

// SelfAttention: B=4, T=4096, D=4096, H=128. fp32 in/out, bf16 MFMA compute.
// R5: 2-phase double-buffered prefetch (T3-minimum) in qkv_proj and flash;
// qkv M=64 (halves Wt L2 re-staging); flash key-split 4->2, removed the
// (wave-private) sP barrier, setprio around MFMA clusters, exact skip-rescale.

typedef __bf16 bf16_t;
typedef bf16_t bf16x8 __attribute__((ext_vector_type(8)));
typedef float f32x4 __attribute__((ext_vector_type(4)));
typedef float f32x8 __attribute__((ext_vector_type(8)));

#define MFMA16(A, B, C) __builtin_amdgcn_mfma_f32_16x16x32_bf16((A), (B), (C), 0, 0, 0)

__device__ __forceinline__ void async_cp16(const bf16_t* g, bf16_t* lds) {
  // 16B direct global->LDS. LDS dest = wave-uniform base + lane*16.
  __builtin_amdgcn_global_load_lds(
      (__attribute__((address_space(1))) unsigned int*)g,
      (__attribute__((address_space(3))) unsigned int*)lds, 16, 0, 0);
}

// ---------------- transpose W: 3x fp32 (4096,128) -> bf16 Wt (384,4096) -------
__global__ void tr_w(const float* __restrict__ w0, const float* __restrict__ w1,
                     const float* __restrict__ w2, bf16_t* __restrict__ wt) {
  __shared__ float tile[32][33];
  const int z = blockIdx.z;
  const float* src = (z == 0) ? w0 : (z == 1) ? w1 : w2;
  bf16_t* dst = wt + (size_t)z * 128 * 4096;
  const int c0 = blockIdx.x * 32;
  const int r0 = blockIdx.y * 32;
  const int tx = threadIdx.x, ty = threadIdx.y;
#pragma unroll
  for (int j = 0; j < 4; ++j)
    tile[ty + 8 * j][tx] = src[(size_t)(r0 + ty + 8 * j) * 128 + c0 + tx];
  __syncthreads();
#pragma unroll
  for (int j = 0; j < 4; ++j)
    dst[(size_t)(c0 + ty + 8 * j) * 4096 + r0 + tx] = (bf16_t)tile[tx][ty + 8 * j];
}

// ---------------- transpose V: bf16 (B,4096,128) -> bf16 Vt (B,128,4096) ------
__global__ void tr_v(const bf16_t* __restrict__ v, bf16_t* __restrict__ vt) {
  __shared__ bf16_t tile[32][33];
  const int b = blockIdx.z;
  const bf16_t* src = v + (size_t)b * 4096 * 128;
  bf16_t* dst = vt + (size_t)b * 128 * 4096;
  const int c0 = blockIdx.x * 32;
  const int r0 = blockIdx.y * 32;
  const int tx = threadIdx.x, ty = threadIdx.y;
#pragma unroll
  for (int j = 0; j < 4; ++j)
    tile[ty + 8 * j][tx] = src[(size_t)(r0 + ty + 8 * j) * 128 + c0 + tx];
  __syncthreads();
#pragma unroll
  for (int j = 0; j < 4; ++j)
    dst[(size_t)(c0 + ty + 8 * j) * 4096 + r0 + tx] = tile[tx][ty + 8 * j];
}

// ---------------- fused QKV projection: fp32 (16384,4096) @ Wt -> 3x bf16 ------
// M=64, N=384, BK=64; 512 threads (8 waves as 2x4), grid 256 (1 block/CU).
// Double-buffered LDS (112 KB): stage kt+1 while computing kt; 1 barrier/kt.
// LDS physical chunk = logical chunk ^ (row & 7) => fragment reads 2-way (free).
__device__ __forceinline__ void stage_b(const bf16_t* __restrict__ wt_k,
                                        bf16_t* sBbuf, int tid) {
#pragma unroll
  for (int r = 0; r < 6; ++r) {  // 3072 chunks of 16B over 512 threads
    int cid = r * 512 + tid;
    int n = cid >> 3, pc = cid & 7;
    int lc = pc ^ (n & 7);
    async_cp16(wt_k + (size_t)n * 4096 + lc * 8, sBbuf + (size_t)cid * 8);
  }
}

__launch_bounds__(512, 2)
__global__ void qkv_proj(const float* __restrict__ x, const bf16_t* __restrict__ wt,
                         bf16_t* __restrict__ q, bf16_t* __restrict__ k,
                         bf16_t* __restrict__ v) {
  __shared__ __align__(16) bf16_t sA[2][64 * 64];    // [m][k], swizzled chunks
  __shared__ __align__(16) bf16_t sB[2][384 * 64];   // [n][k], swizzled chunks
  const int tid = threadIdx.x;
  const int w = tid >> 6, lane = tid & 63, lq = lane & 15, quad = lane >> 4;
  const int wr = w >> 2, wc = w & 3;                 // wave grid 2 (M) x 4 (N)
  const int m0 = blockIdx.x * 64;
  // A staging: thread -> row 0..63, physical chunk 0..7; fetch logical pc^(row&7)
  const int arow = tid >> 3, apc = tid & 7;
  const int alc = apc ^ (arow & 7);
  const float* xrow = x + (size_t)(m0 + arow) * 4096 + alc * 8;

  f32x4 acc[2][6];
#pragma unroll
  for (int i = 0; i < 2; ++i)
#pragma unroll
    for (int j = 0; j < 6; ++j) acc[i][j] = (f32x4){0.f, 0.f, 0.f, 0.f};

  {  // prologue: stage kt=0 into buffer 0
    float4 f0 = ((const float4*)xrow)[0];
    float4 f1 = ((const float4*)xrow)[1];
    stage_b(wt, sB[0], tid);
    f32x8 ff = {f0.x, f0.y, f0.z, f0.w, f1.x, f1.y, f1.z, f1.w};
    *(bf16x8*)(sA[0] + arow * 64 + apc * 8) = __builtin_convertvector(ff, bf16x8);
  }
  __syncthreads();

  for (int kt = 0; kt < 64; ++kt) {
    const int buf = kt & 1;
    float4 f0, f1;
    if (kt < 63) {  // issue next tile's loads BEFORE compute (f-loads first so
                    // the A ds_write below waits vmcnt(6), keeping B in flight)
      const float* xp = xrow + (kt + 1) * 64;
      f0 = ((const float4*)xp)[0];
      f1 = ((const float4*)xp)[1];
      stage_b(wt + (kt + 1) * 64, sB[buf ^ 1], tid);
    }
#pragma unroll
    for (int ks = 0; ks < 2; ++ks) {
      bf16x8 af[2], bfr[6];
      const int cc = ks * 4 + quad;
#pragma unroll
      for (int mt = 0; mt < 2; ++mt) {
        int row = wr * 32 + mt * 16 + lq;
        af[mt] = *(const bf16x8*)(sA[buf] + row * 64 + ((cc ^ (row & 7)) << 3));
      }
#pragma unroll
      for (int nt = 0; nt < 6; ++nt) {
        int n = wc * 96 + nt * 16 + lq;
        bfr[nt] = *(const bf16x8*)(sB[buf] + n * 64 + ((cc ^ (n & 7)) << 3));
      }
#pragma unroll
      for (int mt = 0; mt < 2; ++mt)
#pragma unroll
        for (int nt = 0; nt < 6; ++nt) acc[mt][nt] = MFMA16(af[mt], bfr[nt], acc[mt][nt]);
    }
    if (kt < 63) {  // cvt + swizzled 16B ds_write of next A tile
      f32x8 ff = {f0.x, f0.y, f0.z, f0.w, f1.x, f1.y, f1.z, f1.w};
      *(bf16x8*)(sA[buf ^ 1] + arow * 64 + apc * 8) = __builtin_convertvector(ff, bf16x8);
    }
    __syncthreads();  // drains prefetch; next buffer ready
  }
  // epilogue: C/D layout col(n)=lane&15, row(m)=quad*4+reg
#pragma unroll
  for (int mt = 0; mt < 2; ++mt) {
#pragma unroll
    for (int nt = 0; nt < 6; ++nt) {
      int n = wc * 96 + nt * 16 + lq;
      bf16_t* dst;
      int nn;
      if (n < 128) { dst = q; nn = n; }
      else if (n < 256) { dst = k; nn = n - 128; }
      else { dst = v; nn = n - 256; }
#pragma unroll
      for (int r = 0; r < 4; ++r) {
        int m = m0 + wr * 32 + mt * 16 + quad * 4 + r;
        dst[(size_t)m * 128 + nn] = (bf16_t)acc[mt][nt][r];
      }
    }
  }
}

// ---------------- flash attention, key-split x2, 2-phase prefetch -------------
// Grid 512: b = x&3, qt = (x>>2)&63, sp = x>>8. Block: 64 Q rows, 256 thr;
// wave w owns rows [w*16, w*16+16). Each block does 32 key-tiles of 64 keys.
// Double-buffered sK/sV (73 KB -> 2 blocks/CU); stage i+1 issued before compute
// of i; ONE barrier per iteration (sP is wave-private -> no P barrier).
__device__ __forceinline__ void stage_kv(const bf16_t* __restrict__ ksrc,
                                         const bf16_t* __restrict__ vsrc,
                                         bf16_t* sKbuf, bf16_t* sVbuf, int tid) {
#pragma unroll
  for (int r = 0; r < 4; ++r) {  // K tile: 1024 chunks, swizzle &15
    int cid = r * 256 + tid;
    int row = cid >> 4, pc = cid & 15;
    int lc = pc ^ (row & 15);
    async_cp16(ksrc + row * 128 + lc * 8, sKbuf + (size_t)cid * 8);
  }
#pragma unroll
  for (int r = 0; r < 4; ++r) {  // Vt tile: 1024 chunks, swizzle &7
    int cid = r * 256 + tid;
    int h = cid >> 3, pc = cid & 7;
    int lc = pc ^ (h & 7);
    async_cp16(vsrc + (size_t)h * 4096 + lc * 8, sVbuf + (size_t)cid * 8);
  }
}

__launch_bounds__(256, 2)
__global__ void flash(const bf16_t* __restrict__ q, const bf16_t* __restrict__ kk,
                      const bf16_t* __restrict__ vt, float* __restrict__ opart,
                      float* __restrict__ mlm, float* __restrict__ mll) {
  __shared__ __align__(16) bf16_t sK[2][64 * 128];  // [key][h], swizzled &15
  __shared__ __align__(16) bf16_t sV[2][128 * 64];  // [h][key], swizzled &7
  __shared__ __align__(16) bf16_t sP[64 * 72];      // [qrow][key], wave-private rows
  const int tid = threadIdx.x;
  const int w = tid >> 6, lane = tid & 63, lq = lane & 15, quad = lane >> 4;
  const int b = blockIdx.x & 3;
  const int qt = (blockIdx.x >> 2) & 63;
  const int sp = blockIdx.x >> 8;
  const int qrow0 = qt * 64;

  bf16x8 qf[4];  // Q A-fragments, full head dim
  {
    const bf16_t* qp = q + ((size_t)b * 4096 + qrow0 + w * 16 + lq) * 128 + quad * 8;
#pragma unroll
    for (int ks = 0; ks < 4; ++ks) qf[ks] = *(const bf16x8*)(qp + ks * 32);
  }

  f32x4 accO[8];
#pragma unroll
  for (int i = 0; i < 8; ++i) accO[i] = (f32x4){0.f, 0.f, 0.f, 0.f};
  float mrow[4] = {-1e30f, -1e30f, -1e30f, -1e30f};
  float lrow[4] = {0.f, 0.f, 0.f, 0.f};

  const bf16_t* kbase = kk + (size_t)b * 4096 * 128;
  const bf16_t* vbase = vt + (size_t)b * 128 * 4096;
  const float SCL = 0.08838834764831845f * 1.4426950408889634f;  // 1/sqrt(128)*log2(e)
  const int it0 = sp * 32;

  stage_kv(kbase + (size_t)it0 * 64 * 128, vbase + it0 * 64, sK[0], sV[0], tid);
  __syncthreads();  // buffer 0 ready

  for (int i = 0; i < 32; ++i) {
    const int buf = i & 1;
    if (i < 31)  // prefetch next tile into other buffer; stays in flight through
                 // the whole compute phase (no mid-iteration vmcnt drain)
      stage_kv(kbase + (size_t)(it0 + i + 1) * 64 * 128, vbase + (it0 + i + 1) * 64,
               sK[buf ^ 1], sV[buf ^ 1], tid);

    // --- S = Q K^T: this wave's 16 rows x 64 keys ---
    f32x4 accS[4];
#pragma unroll
    for (int nt = 0; nt < 4; ++nt) accS[nt] = (f32x4){0.f, 0.f, 0.f, 0.f};
    __builtin_amdgcn_s_setprio(1);
#pragma unroll
    for (int ks = 0; ks < 4; ++ks) {
      const int cc = ks * 4 + quad;
#pragma unroll
      for (int nt = 0; nt < 4; ++nt) {
        int row = nt * 16 + lq;
        bf16x8 kf = *(const bf16x8*)(sK[buf] + row * 128 + ((cc ^ (row & 15)) << 3));
        accS[nt] = MFMA16(qf[ks], kf, accS[nt]);
      }
    }
    __builtin_amdgcn_s_setprio(0);

    // --- online softmax: rows = quad*4+r, cols = lane&15 ---
    // max in raw domain, SCL folded into the exp via fma (saves 16 muls/iter)
    float mxs[4];
#pragma unroll
    for (int r = 0; r < 4; ++r) {
      float t0 = fmaxf(fmaxf(accS[0][r], accS[1][r]), fmaxf(accS[2][r], accS[3][r]));
#pragma unroll
      for (int msk = 1; msk < 16; msk <<= 1) t0 = fmaxf(t0, __shfl_xor(t0, msk));
      mxs[r] = t0 * SCL;
    }
    // exact skip: when no row max grows, al==1 -> rescale is identity
    bool grow = (mxs[0] > mrow[0]) || (mxs[1] > mrow[1]) ||
                (mxs[2] > mrow[2]) || (mxs[3] > mrow[3]);
    if (__any(grow)) {
      float al[4];
#pragma unroll
      for (int r = 0; r < 4; ++r) {
        float mn = fmaxf(mrow[r], mxs[r]);
        al[r] = exp2f(mrow[r] - mn);
        mrow[r] = mn;
        lrow[r] *= al[r];
      }
#pragma unroll
      for (int ot = 0; ot < 8; ++ot) {
        accO[ot][0] *= al[0]; accO[ot][1] *= al[1];
        accO[ot][2] *= al[2]; accO[ot][3] *= al[3];
      }
    }
    float ps[4] = {0.f, 0.f, 0.f, 0.f};
#pragma unroll
    for (int nt = 0; nt < 4; ++nt)
#pragma unroll
      for (int r = 0; r < 4; ++r) {
        float p = exp2f(fmaf(accS[nt][r], SCL, -mrow[r]));
        accS[nt][r] = p;
        ps[r] += p;
      }
#pragma unroll
    for (int r = 0; r < 4; ++r) {
      float s = ps[r];
#pragma unroll
      for (int msk = 1; msk < 16; msk <<= 1) s += __shfl_xor(s, msk);
      lrow[r] += s;
    }

    // --- write P (bf16) to sP[qrow][key]; rows are wave-private, no barrier ---
#pragma unroll
    for (int nt = 0; nt < 4; ++nt) {
      int key = nt * 16 + lq;
#pragma unroll
      for (int r = 0; r < 4; ++r) {
        int prow = w * 16 + quad * 4 + r;
        sP[prow * 72 + key] = (bf16_t)accS[nt][r];
      }
    }

    // --- O += P V (compiler inserts lgkmcnt for the sP write->read dep) ---
    __builtin_amdgcn_s_setprio(1);
#pragma unroll
    for (int ks2 = 0; ks2 < 2; ++ks2) {
      const int cc = ks2 * 4 + quad;
      bf16x8 pf = *(const bf16x8*)(sP + (w * 16 + lq) * 72 + cc * 8);
#pragma unroll
      for (int ot = 0; ot < 8; ++ot) {
        int h = ot * 16 + lq;
        bf16x8 vf = *(const bf16x8*)(sV[buf] + h * 64 + ((cc ^ (h & 7)) << 3));
        accO[ot] = MFMA16(pf, vf, accO[ot]);
      }
    }
    __builtin_amdgcn_s_setprio(0);
    __syncthreads();  // drains prefetch vmcnt + all reads of buf; swap buffers
  }

  // --- store fp32 partials (unnormalized) + m,l ---
  float* op = opart + ((size_t)(sp * 4 + b) * 4096 + qrow0 + w * 16) * 128;
#pragma unroll
  for (int ot = 0; ot < 8; ++ot)
#pragma unroll
    for (int r = 0; r < 4; ++r)
      op[(size_t)(quad * 4 + r) * 128 + ot * 16 + lq] = accO[ot][r];
  if (lq == 0) {
#pragma unroll
    for (int r = 0; r < 4; ++r) {
      size_t idx = (size_t)(sp * 4 + b) * 4096 + qrow0 + w * 16 + quad * 4 + r;
      mlm[idx] = mrow[r];
      mll[idx] = lrow[r];
    }
  }
}

// ---------------- merge the 2 key-splits --------------------------------------
__global__ void merge(const float* __restrict__ opart, const float* __restrict__ mlm,
                      const float* __restrict__ mll, float* __restrict__ out) {
  const int idx = blockIdx.x * 256 + threadIdx.x;  // 2M elements
  const int h = idx & 127;
  const int row = idx >> 7;  // b*4096 + t
  float m0 = mlm[row], m1 = mlm[16384 + row];
  float l0 = mll[row], l1 = mll[16384 + row];
  float M = fmaxf(m0, m1);
  float w0 = exp2f(m0 - M), w1 = exp2f(m1 - M);
  float L = w0 * l0 + w1 * l1;
  float acc = w0 * opart[(size_t)row * 128 + h] +
              w1 * opart[((size_t)16384 + row) * 128 + h];
  out[idx] = acc / L;
}

extern "C" void kernel_launch(void* const* d_in, const int* in_sizes, int n_in,
                              void* d_out, int out_size, void* d_ws, size_t ws_size,
                              hipStream_t stream) {
  (void)in_sizes; (void)n_in; (void)out_size; (void)ws_size;
  const float* x  = (const float*)d_in[0];
  const float* wq = (const float*)d_in[1];
  const float* wk = (const float*)d_in[2];
  const float* wv = (const float*)d_in[3];

  char* ws = (char*)d_ws;
  bf16_t* wt  = (bf16_t*)ws;                         ws += (size_t)384 * 4096 * 2;
  bf16_t* qb  = (bf16_t*)ws;                         ws += (size_t)16384 * 128 * 2;
  bf16_t* kb  = (bf16_t*)ws;                         ws += (size_t)16384 * 128 * 2;
  bf16_t* vb  = (bf16_t*)ws;                         ws += (size_t)16384 * 128 * 2;
  bf16_t* vtb = (bf16_t*)ws;                         ws += (size_t)16384 * 128 * 2;
  float*  opart = (float*)ws;                        ws += (size_t)2 * 16384 * 128 * 4;
  float*  mlm = (float*)ws;                          ws += (size_t)2 * 16384 * 4;
  float*  mll = (float*)ws;
  float*  ob  = (float*)d_out;

  dim3 tb(32, 8, 1);
  tr_w<<<dim3(4, 128, 3), tb, 0, stream>>>(wq, wk, wv, wt);
  qkv_proj<<<dim3(256), dim3(512), 0, stream>>>(x, wt, qb, kb, vb);
  tr_v<<<dim3(4, 128, 4), tb, 0, stream>>>(vb, vtb);
  flash<<<dim3(512), dim3(256), 0, stream>>>(qb, kb, vtb, opart, mlm, mll);
  merge<<<dim3(8192), dim3(256), 0, stream>>>(opart, mlm, mll, ob);
}

// Round 2
// 513.832 us; speedup vs baseline: 1.0342x; 1.0295x over previous
//
#include <hip/hip_runtime.h>

// SelfAttention: B=4, T=4096, D=4096, H=128. fp32 in/out, bf16 MFMA compute.
// R6: qkv_proj rebuilt as counted-vmcnt pipeline (T4): 256 thr, M=64 x N=192,
// 64 KB LDS -> 2 blocks/CU, raw s_barrier with vmcnt(4) (never drains to 0);
// A register-staged 2 tiles ahead. flash/tr/merge unchanged from R5.

typedef __bf16 bf16_t;
typedef bf16_t bf16x8 __attribute__((ext_vector_type(8)));
typedef float f32x4 __attribute__((ext_vector_type(4)));
typedef float f32x8 __attribute__((ext_vector_type(8)));

#define MFMA16(A, B, C) __builtin_amdgcn_mfma_f32_16x16x32_bf16((A), (B), (C), 0, 0, 0)

__device__ __forceinline__ void async_cp16(const bf16_t* g, bf16_t* lds) {
  // 16B direct global->LDS. LDS dest = wave-uniform base + lane*16.
  __builtin_amdgcn_global_load_lds(
      (__attribute__((address_space(1))) unsigned int*)g,
      (__attribute__((address_space(3))) unsigned int*)lds, 16, 0, 0);
}

// ---------------- transpose W: 3x fp32 (4096,128) -> bf16 Wt (384,4096) -------
__global__ void tr_w(const float* __restrict__ w0, const float* __restrict__ w1,
                     const float* __restrict__ w2, bf16_t* __restrict__ wt) {
  __shared__ float tile[32][33];
  const int z = blockIdx.z;
  const float* src = (z == 0) ? w0 : (z == 1) ? w1 : w2;
  bf16_t* dst = wt + (size_t)z * 128 * 4096;
  const int c0 = blockIdx.x * 32;
  const int r0 = blockIdx.y * 32;
  const int tx = threadIdx.x, ty = threadIdx.y;
#pragma unroll
  for (int j = 0; j < 4; ++j)
    tile[ty + 8 * j][tx] = src[(size_t)(r0 + ty + 8 * j) * 128 + c0 + tx];
  __syncthreads();
#pragma unroll
  for (int j = 0; j < 4; ++j)
    dst[(size_t)(c0 + ty + 8 * j) * 4096 + r0 + tx] = (bf16_t)tile[tx][ty + 8 * j];
}

// ---------------- transpose V: bf16 (B,4096,128) -> bf16 Vt (B,128,4096) ------
__global__ void tr_v(const bf16_t* __restrict__ v, bf16_t* __restrict__ vt) {
  __shared__ bf16_t tile[32][33];
  const int b = blockIdx.z;
  const bf16_t* src = v + (size_t)b * 4096 * 128;
  bf16_t* dst = vt + (size_t)b * 128 * 4096;
  const int c0 = blockIdx.x * 32;
  const int r0 = blockIdx.y * 32;
  const int tx = threadIdx.x, ty = threadIdx.y;
#pragma unroll
  for (int j = 0; j < 4; ++j)
    tile[ty + 8 * j][tx] = src[(size_t)(r0 + ty + 8 * j) * 128 + c0 + tx];
  __syncthreads();
#pragma unroll
  for (int j = 0; j < 4; ++j)
    dst[(size_t)(c0 + ty + 8 * j) * 4096 + r0 + tx] = tile[tx][ty + 8 * j];
}

// ---------------- fused QKV projection: fp32 (16384,4096) @ Wt -> 3x bf16 ------
// M=64, N=192 (half of 384), BK=64; 256 threads (4 waves as 2x2), grid 512
// (2 blocks/CU). Pipeline (counted vmcnt, never 0 in loop):
//   iter kt: issue B(kt+1) gload_lds [6 ops] -> cvt+ds_write A(kt+1) (regs from
//   last iter; compiler inserts vmcnt(6)) -> issue A(kt+2) reg loads [4 ops]
//   -> 24 MFMA on buf kt -> s_waitcnt vmcnt(4) lgkmcnt(0) -> s_barrier.
// A-loads get ~2 iterations of latency cover; B stays in flight across compute.
__device__ __forceinline__ void stage_b(const bf16_t* __restrict__ wt_k,
                                        bf16_t* sBbuf, int tid) {
#pragma unroll
  for (int r = 0; r < 6; ++r) {  // 1536 chunks of 16B over 256 threads
    int cid = r * 256 + tid;
    int n = cid >> 3, pc = cid & 7;
    int lc = pc ^ (n & 7);
    async_cp16(wt_k + (size_t)n * 4096 + lc * 8, sBbuf + (size_t)cid * 8);
  }
}

__launch_bounds__(256, 2)
__global__ void qkv_proj(const float* __restrict__ x, const bf16_t* __restrict__ wt,
                         bf16_t* __restrict__ q, bf16_t* __restrict__ k,
                         bf16_t* __restrict__ v) {
  __shared__ __align__(16) bf16_t sA[2][64 * 64];    // 2 x 8 KB, swizzled chunks
  __shared__ __align__(16) bf16_t sB[2][192 * 64];   // 2 x 24 KB, swizzled chunks
  const int tid = threadIdx.x;
  const int w = tid >> 6, lane = tid & 63, lq = lane & 15, quad = lane >> 4;
  const int wr = w >> 1, wc = w & 1;                 // wave grid 2 (M) x 2 (N)
  const int m0 = (int)(blockIdx.x >> 1) * 64;
  const int nb = (int)(blockIdx.x & 1) * 192;        // which N-half of Wt
  const bf16_t* wtb = wt + (size_t)nb * 4096;

  // A staging: 2 chunks (16B bf16 = 8 fp32) per thread.
  int arow[2], apc[2], alc[2];
#pragma unroll
  for (int r = 0; r < 2; ++r) {
    int ca = r * 256 + tid;
    arow[r] = ca >> 3;
    apc[r] = ca & 7;
    alc[r] = apc[r] ^ (arow[r] & 7);
  }
  const float* xb = x + (size_t)m0 * 4096;

  f32x4 acc[2][6];
#pragma unroll
  for (int i = 0; i < 2; ++i)
#pragma unroll
    for (int j = 0; j < 6; ++j) acc[i][j] = (f32x4){0.f, 0.f, 0.f, 0.f};

  float4 fA[4];
  // ---- prologue: A(0) regs, B(0)->sB[0], write sA[0], A(1) regs ----
#pragma unroll
  for (int r = 0; r < 2; ++r) {
    const float4* p = (const float4*)(xb + (size_t)arow[r] * 4096 + alc[r] * 8);
    fA[2 * r] = p[0];
    fA[2 * r + 1] = p[1];
  }
  stage_b(wtb, sB[0], tid);
#pragma unroll
  for (int r = 0; r < 2; ++r) {
    f32x8 ff = {fA[2 * r].x, fA[2 * r].y, fA[2 * r].z, fA[2 * r].w,
                fA[2 * r + 1].x, fA[2 * r + 1].y, fA[2 * r + 1].z, fA[2 * r + 1].w};
    *(bf16x8*)(sA[0] + arow[r] * 64 + apc[r] * 8) = __builtin_convertvector(ff, bf16x8);
  }
#pragma unroll
  for (int r = 0; r < 2; ++r) {
    const float4* p = (const float4*)(xb + (size_t)arow[r] * 4096 + 64 + alc[r] * 8);
    fA[2 * r] = p[0];
    fA[2 * r + 1] = p[1];
  }
  asm volatile("s_waitcnt vmcnt(4) lgkmcnt(0)" ::: "memory");
  __builtin_amdgcn_s_barrier();

  for (int kt = 0; kt < 64; ++kt) {
    const int buf = kt & 1;
    // issue B(kt+1) (clamped dummy on last iter keeps vmcnt counts uniform;
    // writes sB[buf^1] whose tile-(kt-1) readers finished before last barrier)
    const int ktB = (kt < 63) ? kt + 1 : 63;
    stage_b(wtb + ktB * 64, sB[buf ^ 1], tid);
    // cvt + swizzled ds_write of A(kt+1) (compiler waits vmcnt(6) for fA)
#pragma unroll
    for (int r = 0; r < 2; ++r) {
      f32x8 ff = {fA[2 * r].x, fA[2 * r].y, fA[2 * r].z, fA[2 * r].w,
                  fA[2 * r + 1].x, fA[2 * r + 1].y, fA[2 * r + 1].z, fA[2 * r + 1].w};
      *(bf16x8*)(sA[buf ^ 1] + arow[r] * 64 + apc[r] * 8) =
          __builtin_convertvector(ff, bf16x8);
    }
    // issue A(kt+2) reg loads (clamped at tail)
    const int ktA = (kt < 62) ? kt + 2 : 63;
#pragma unroll
    for (int r = 0; r < 2; ++r) {
      const float4* p =
          (const float4*)(xb + (size_t)arow[r] * 4096 + ktA * 64 + alc[r] * 8);
      fA[2 * r] = p[0];
      fA[2 * r + 1] = p[1];
    }
    // compute tile kt from sA[buf], sB[buf]
#pragma unroll
    for (int ks = 0; ks < 2; ++ks) {
      bf16x8 af[2], bfr[6];
      const int cc = ks * 4 + quad;
#pragma unroll
      for (int mt = 0; mt < 2; ++mt) {
        int row = wr * 32 + mt * 16 + lq;
        af[mt] = *(const bf16x8*)(sA[buf] + row * 64 + ((cc ^ (row & 7)) << 3));
      }
#pragma unroll
      for (int nt = 0; nt < 6; ++nt) {
        int n = wc * 96 + nt * 16 + lq;
        bfr[nt] = *(const bf16x8*)(sB[buf] + n * 64 + ((cc ^ (n & 7)) << 3));
      }
#pragma unroll
      for (int mt = 0; mt < 2; ++mt)
#pragma unroll
        for (int nt = 0; nt < 6; ++nt) acc[mt][nt] = MFMA16(af[mt], bfr[nt], acc[mt][nt]);
    }
    // retire exactly B(kt+1) [oldest 6 of 10]; A(kt+2) stays in flight.
    asm volatile("s_waitcnt vmcnt(4) lgkmcnt(0)" ::: "memory");
    __builtin_amdgcn_s_barrier();
  }
  // epilogue: C/D layout col(n)=lane&15, row(m)=quad*4+reg
#pragma unroll
  for (int mt = 0; mt < 2; ++mt) {
#pragma unroll
    for (int nt = 0; nt < 6; ++nt) {
      int n = nb + wc * 96 + nt * 16 + lq;
      bf16_t* dst;
      int nn;
      if (n < 128) { dst = q; nn = n; }
      else if (n < 256) { dst = k; nn = n - 128; }
      else { dst = v; nn = n - 256; }
#pragma unroll
      for (int r = 0; r < 4; ++r) {
        int m = m0 + wr * 32 + mt * 16 + quad * 4 + r;
        dst[(size_t)m * 128 + nn] = (bf16_t)acc[mt][nt][r];
      }
    }
  }
}

// ---------------- flash attention, key-split x2, 2-phase prefetch -------------
// Grid 512: b = x&3, qt = (x>>2)&63, sp = x>>8. Block: 64 Q rows, 256 thr;
// wave w owns rows [w*16, w*16+16). Each block does 32 key-tiles of 64 keys.
// Double-buffered sK/sV (73 KB -> 2 blocks/CU); stage i+1 issued before compute
// of i; ONE barrier per iteration (sP is wave-private -> no P barrier).
__device__ __forceinline__ void stage_kv(const bf16_t* __restrict__ ksrc,
                                         const bf16_t* __restrict__ vsrc,
                                         bf16_t* sKbuf, bf16_t* sVbuf, int tid) {
#pragma unroll
  for (int r = 0; r < 4; ++r) {  // K tile: 1024 chunks, swizzle &15
    int cid = r * 256 + tid;
    int row = cid >> 4, pc = cid & 15;
    int lc = pc ^ (row & 15);
    async_cp16(ksrc + row * 128 + lc * 8, sKbuf + (size_t)cid * 8);
  }
#pragma unroll
  for (int r = 0; r < 4; ++r) {  // Vt tile: 1024 chunks, swizzle &7
    int cid = r * 256 + tid;
    int h = cid >> 3, pc = cid & 7;
    int lc = pc ^ (h & 7);
    async_cp16(vsrc + (size_t)h * 4096 + lc * 8, sVbuf + (size_t)cid * 8);
  }
}

__launch_bounds__(256, 2)
__global__ void flash(const bf16_t* __restrict__ q, const bf16_t* __restrict__ kk,
                      const bf16_t* __restrict__ vt, float* __restrict__ opart,
                      float* __restrict__ mlm, float* __restrict__ mll) {
  __shared__ __align__(16) bf16_t sK[2][64 * 128];  // [key][h], swizzled &15
  __shared__ __align__(16) bf16_t sV[2][128 * 64];  // [h][key], swizzled &7
  __shared__ __align__(16) bf16_t sP[64 * 72];      // [qrow][key], wave-private rows
  const int tid = threadIdx.x;
  const int w = tid >> 6, lane = tid & 63, lq = lane & 15, quad = lane >> 4;
  const int b = blockIdx.x & 3;
  const int qt = (blockIdx.x >> 2) & 63;
  const int sp = blockIdx.x >> 8;
  const int qrow0 = qt * 64;

  bf16x8 qf[4];  // Q A-fragments, full head dim
  {
    const bf16_t* qp = q + ((size_t)b * 4096 + qrow0 + w * 16 + lq) * 128 + quad * 8;
#pragma unroll
    for (int ks = 0; ks < 4; ++ks) qf[ks] = *(const bf16x8*)(qp + ks * 32);
  }

  f32x4 accO[8];
#pragma unroll
  for (int i = 0; i < 8; ++i) accO[i] = (f32x4){0.f, 0.f, 0.f, 0.f};
  float mrow[4] = {-1e30f, -1e30f, -1e30f, -1e30f};
  float lrow[4] = {0.f, 0.f, 0.f, 0.f};

  const bf16_t* kbase = kk + (size_t)b * 4096 * 128;
  const bf16_t* vbase = vt + (size_t)b * 128 * 4096;
  const float SCL = 0.08838834764831845f * 1.4426950408889634f;  // 1/sqrt(128)*log2(e)
  const int it0 = sp * 32;

  stage_kv(kbase + (size_t)it0 * 64 * 128, vbase + it0 * 64, sK[0], sV[0], tid);
  __syncthreads();  // buffer 0 ready

  for (int i = 0; i < 32; ++i) {
    const int buf = i & 1;
    if (i < 31)  // prefetch next tile into other buffer; stays in flight through
                 // the whole compute phase (no mid-iteration vmcnt drain)
      stage_kv(kbase + (size_t)(it0 + i + 1) * 64 * 128, vbase + (it0 + i + 1) * 64,
               sK[buf ^ 1], sV[buf ^ 1], tid);

    // --- S = Q K^T: this wave's 16 rows x 64 keys ---
    f32x4 accS[4];
#pragma unroll
    for (int nt = 0; nt < 4; ++nt) accS[nt] = (f32x4){0.f, 0.f, 0.f, 0.f};
    __builtin_amdgcn_s_setprio(1);
#pragma unroll
    for (int ks = 0; ks < 4; ++ks) {
      const int cc = ks * 4 + quad;
#pragma unroll
      for (int nt = 0; nt < 4; ++nt) {
        int row = nt * 16 + lq;
        bf16x8 kf = *(const bf16x8*)(sK[buf] + row * 128 + ((cc ^ (row & 15)) << 3));
        accS[nt] = MFMA16(qf[ks], kf, accS[nt]);
      }
    }
    __builtin_amdgcn_s_setprio(0);

    // --- online softmax: rows = quad*4+r, cols = lane&15 ---
    // max in raw domain, SCL folded into the exp via fma (saves 16 muls/iter)
    float mxs[4];
#pragma unroll
    for (int r = 0; r < 4; ++r) {
      float t0 = fmaxf(fmaxf(accS[0][r], accS[1][r]), fmaxf(accS[2][r], accS[3][r]));
#pragma unroll
      for (int msk = 1; msk < 16; msk <<= 1) t0 = fmaxf(t0, __shfl_xor(t0, msk));
      mxs[r] = t0 * SCL;
    }
    // exact skip: when no row max grows, al==1 -> rescale is identity
    bool grow = (mxs[0] > mrow[0]) || (mxs[1] > mrow[1]) ||
                (mxs[2] > mrow[2]) || (mxs[3] > mrow[3]);
    if (__any(grow)) {
      float al[4];
#pragma unroll
      for (int r = 0; r < 4; ++r) {
        float mn = fmaxf(mrow[r], mxs[r]);
        al[r] = exp2f(mrow[r] - mn);
        mrow[r] = mn;
        lrow[r] *= al[r];
      }
#pragma unroll
      for (int ot = 0; ot < 8; ++ot) {
        accO[ot][0] *= al[0]; accO[ot][1] *= al[1];
        accO[ot][2] *= al[2]; accO[ot][3] *= al[3];
      }
    }
    float ps[4] = {0.f, 0.f, 0.f, 0.f};
#pragma unroll
    for (int nt = 0; nt < 4; ++nt)
#pragma unroll
      for (int r = 0; r < 4; ++r) {
        float p = exp2f(fmaf(accS[nt][r], SCL, -mrow[r]));
        accS[nt][r] = p;
        ps[r] += p;
      }
#pragma unroll
    for (int r = 0; r < 4; ++r) {
      float s = ps[r];
#pragma unroll
      for (int msk = 1; msk < 16; msk <<= 1) s += __shfl_xor(s, msk);
      lrow[r] += s;
    }

    // --- write P (bf16) to sP[qrow][key]; rows are wave-private, no barrier ---
#pragma unroll
    for (int nt = 0; nt < 4; ++nt) {
      int key = nt * 16 + lq;
#pragma unroll
      for (int r = 0; r < 4; ++r) {
        int prow = w * 16 + quad * 4 + r;
        sP[prow * 72 + key] = (bf16_t)accS[nt][r];
      }
    }

    // --- O += P V (compiler inserts lgkmcnt for the sP write->read dep) ---
    __builtin_amdgcn_s_setprio(1);
#pragma unroll
    for (int ks2 = 0; ks2 < 2; ++ks2) {
      const int cc = ks2 * 4 + quad;
      bf16x8 pf = *(const bf16x8*)(sP + (w * 16 + lq) * 72 + cc * 8);
#pragma unroll
      for (int ot = 0; ot < 8; ++ot) {
        int h = ot * 16 + lq;
        bf16x8 vf = *(const bf16x8*)(sV[buf] + h * 64 + ((cc ^ (h & 7)) << 3));
        accO[ot] = MFMA16(pf, vf, accO[ot]);
      }
    }
    __builtin_amdgcn_s_setprio(0);
    __syncthreads();  // drains prefetch vmcnt + all reads of buf; swap buffers
  }

  // --- store fp32 partials (unnormalized) + m,l ---
  float* op = opart + ((size_t)(sp * 4 + b) * 4096 + qrow0 + w * 16) * 128;
#pragma unroll
  for (int ot = 0; ot < 8; ++ot)
#pragma unroll
    for (int r = 0; r < 4; ++r)
      op[(size_t)(quad * 4 + r) * 128 + ot * 16 + lq] = accO[ot][r];
  if (lq == 0) {
#pragma unroll
    for (int r = 0; r < 4; ++r) {
      size_t idx = (size_t)(sp * 4 + b) * 4096 + qrow0 + w * 16 + quad * 4 + r;
      mlm[idx] = mrow[r];
      mll[idx] = lrow[r];
    }
  }
}

// ---------------- merge the 2 key-splits --------------------------------------
__global__ void merge(const float* __restrict__ opart, const float* __restrict__ mlm,
                      const float* __restrict__ mll, float* __restrict__ out) {
  const int idx = blockIdx.x * 256 + threadIdx.x;  // 2M elements
  const int h = idx & 127;
  const int row = idx >> 7;  // b*4096 + t
  float m0 = mlm[row], m1 = mlm[16384 + row];
  float l0 = mll[row], l1 = mll[16384 + row];
  float M = fmaxf(m0, m1);
  float w0 = exp2f(m0 - M), w1 = exp2f(m1 - M);
  float L = w0 * l0 + w1 * l1;
  float acc = w0 * opart[(size_t)row * 128 + h] +
              w1 * opart[((size_t)16384 + row) * 128 + h];
  out[idx] = acc / L;
}

extern "C" void kernel_launch(void* const* d_in, const int* in_sizes, int n_in,
                              void* d_out, int out_size, void* d_ws, size_t ws_size,
                              hipStream_t stream) {
  (void)in_sizes; (void)n_in; (void)out_size; (void)ws_size;
  const float* x  = (const float*)d_in[0];
  const float* wq = (const float*)d_in[1];
  const float* wk = (const float*)d_in[2];
  const float* wv = (const float*)d_in[3];

  char* ws = (char*)d_ws;
  bf16_t* wt  = (bf16_t*)ws;                         ws += (size_t)384 * 4096 * 2;
  bf16_t* qb  = (bf16_t*)ws;                         ws += (size_t)16384 * 128 * 2;
  bf16_t* kb  = (bf16_t*)ws;                         ws += (size_t)16384 * 128 * 2;
  bf16_t* vb  = (bf16_t*)ws;                         ws += (size_t)16384 * 128 * 2;
  bf16_t* vtb = (bf16_t*)ws;                         ws += (size_t)16384 * 128 * 2;
  float*  opart = (float*)ws;                        ws += (size_t)2 * 16384 * 128 * 4;
  float*  mlm = (float*)ws;                          ws += (size_t)2 * 16384 * 4;
  float*  mll = (float*)ws;
  float*  ob  = (float*)d_out;

  dim3 tb(32, 8, 1);
  tr_w<<<dim3(4, 128, 3), tb, 0, stream>>>(wq, wk, wv, wt);
  qkv_proj<<<dim3(512), dim3(256), 0, stream>>>(x, wt, qb, kb, vb);
  tr_v<<<dim3(4, 128, 4), tb, 0, stream>>>(vb, vtb);
  flash<<<dim3(512), dim3(256), 0, stream>>>(qb, kb, vtb, opart, mlm, mll);
  merge<<<dim3(8192), dim3(256), 0, stream>>>(opart, mlm, mll, ob);
}